// Round 2
// 606.645 us; speedup vs baseline: 1.3629x; 1.3629x over previous
//
#include <hip/hip_runtime.h>
#include <hip/hip_bf16.h>

typedef __bf16 bf16_t;
typedef __attribute__((ext_vector_type(4))) __bf16 bf16x4;
typedef __attribute__((ext_vector_type(8))) __bf16 bf16x8;
typedef __attribute__((ext_vector_type(4))) float f32x4;

#define DIM 128

// async global->LDS, 16B per lane. LDS dest = wave-uniform base + lane*16.
__device__ __forceinline__ void gl_lds16(const void* g, void* l) {
    __builtin_amdgcn_global_load_lds(
        (const __attribute__((address_space(1))) unsigned int*)g,
        (__attribute__((address_space(3))) unsigned int*)l, 16, 0, 0);
}

// ---------------- weight prep: Wc[s][n][k256] bf16, s = layer*2 + type ----------
__global__ void prep_weights(const float* __restrict__ Wl, const float* __restrict__ Wr,
                             bf16_t* __restrict__ Wc) {
    int idx = blockIdx.x * blockDim.x + threadIdx.x;   // over 6*128*256
    if (idx >= 6 * 128 * 256) return;
    int k = idx & 255;
    int n = (idx >> 8) & 127;
    int s = idx >> 15;                                  // 0..5
    float v;
    if (k < 128) v = Wl[((size_t)s * 128 + n) * 128 + k];
    else         v = Wr[((size_t)s * 128 + n) * 128 + (k - 128)];
    Wc[idx] = (bf16_t)v;
}

// ---------------- degree count (both edge types in one launch) ----------------
__global__ void count_edges2(const int* __restrict__ dA, int* __restrict__ cA,
                             const int* __restrict__ dB, int* __restrict__ cB, int E) {
    int i = blockIdx.x * blockDim.x + threadIdx.x;
    if (i < E) atomicAdd(&cA[dA[i]], 1);
    else if (i < 2 * E) atomicAdd(&cB[dB[i - E]], 1);
}

// ---------------- CSR build: block scan ----------------
__global__ __launch_bounds__(256) void scan_local(const int* __restrict__ cnt,
                                                  int* __restrict__ partial,
                                                  int* __restrict__ blocksum, int M) {
    __shared__ int sdata[256];
    int i = blockIdx.x * 256 + threadIdx.x;
    int v = (i < M) ? cnt[i] : 0;
    sdata[threadIdx.x] = v;
    __syncthreads();
    for (int off = 1; off < 256; off <<= 1) {
        int t = (threadIdx.x >= off) ? sdata[threadIdx.x - off] : 0;
        __syncthreads();
        sdata[threadIdx.x] += t;
        __syncthreads();
    }
    int incl = sdata[threadIdx.x];
    if (i < M) partial[i] = incl - v;
    if (threadIdx.x == 255) blocksum[blockIdx.x] = incl;
}

__global__ __launch_bounds__(256) void scan_blocks(int* __restrict__ blocksum, int NB) {
    __shared__ int sdata[256];
    __shared__ int running;
    if (threadIdx.x == 0) running = 0;
    __syncthreads();
    for (int base = 0; base < NB; base += 256) {
        int i = base + threadIdx.x;
        int v = (i < NB) ? blocksum[i] : 0;
        sdata[threadIdx.x] = v;
        __syncthreads();
        for (int off = 1; off < 256; off <<= 1) {
            int t = (threadIdx.x >= off) ? sdata[threadIdx.x - off] : 0;
            __syncthreads();
            sdata[threadIdx.x] += t;
            __syncthreads();
        }
        int incl = sdata[threadIdx.x];
        int r = running;
        __syncthreads();
        if (i < NB) blocksum[i] = incl - v + r;
        if (threadIdx.x == 0) running = r + sdata[255];
        __syncthreads();
    }
}

__global__ void add_offsets(const int* __restrict__ partial, const int* __restrict__ blocksum,
                            int* __restrict__ rowstart, int* __restrict__ cursor, int M) {
    int i = blockIdx.x * blockDim.x + threadIdx.x;
    if (i < M) {
        int rs = partial[i] + blocksum[i >> 8];
        rowstart[i] = rs;
        cursor[i] = rs;
    }
}

__global__ void bin_edges2(const int* __restrict__ sA, const int* __restrict__ dA,
                           int* __restrict__ curA, int* __restrict__ csrA,
                           const int* __restrict__ sB, const int* __restrict__ dB,
                           int* __restrict__ curB, int* __restrict__ csrB, int E) {
    int e = blockIdx.x * blockDim.x + threadIdx.x;
    if (e < E) {
        int d = dA[e];
        int pos = atomicAdd(&curA[d], 1);
        csrA[pos] = sA[e];
    } else if (e < 2 * E) {
        int i = e - E;
        int d = dB[i];
        int pos = atomicAdd(&curB[d], 1);
        csrB[pos] = sB[i];
    }
}

// ---------------- gather-mean -> bf16: 2 dst rows per wave, float4 per lane ------
__global__ __launch_bounds__(256) void gather_mean_bf16(
    const float* __restrict__ xsrc, const int* __restrict__ rowstart,
    const int* __restrict__ cnt, const int* __restrict__ csr_src,
    bf16_t* __restrict__ agg, int M) {
    int wid  = (blockIdx.x * 256 + threadIdx.x) >> 6;
    int lane = threadIdx.x & 63;
    int half = lane >> 5;
    int l32  = lane & 31;
    int d = wid * 2 + half;
    if (d >= M) return;
    int start = rowstart[d];
    int n = cnt[d];
    float4 acc0 = {0.f, 0.f, 0.f, 0.f};
    float4 acc1 = {0.f, 0.f, 0.f, 0.f};
    int k = 0;
    for (; k + 1 < n; k += 2) {
        int s0 = csr_src[start + k];
        int s1 = csr_src[start + k + 1];
        float4 v0 = ((const float4*)(xsrc + (size_t)s0 * DIM))[l32];
        float4 v1 = ((const float4*)(xsrc + (size_t)s1 * DIM))[l32];
        acc0.x += v0.x; acc0.y += v0.y; acc0.z += v0.z; acc0.w += v0.w;
        acc1.x += v1.x; acc1.y += v1.y; acc1.z += v1.z; acc1.w += v1.w;
    }
    if (k < n) {
        int s = csr_src[start + k];
        float4 v = ((const float4*)(xsrc + (size_t)s * DIM))[l32];
        acc0.x += v.x; acc0.y += v.y; acc0.z += v.z; acc0.w += v.w;
    }
    float invn = 1.0f / (float)max(n, 1);
    bf16x4 r;
    r[0] = (bf16_t)((acc0.x + acc1.x) * invn);
    r[1] = (bf16_t)((acc0.y + acc1.y) * invn);
    r[2] = (bf16_t)((acc0.z + acc1.z) * invn);
    r[3] = (bf16_t)((acc0.w + acc1.w) * invn);
    *(bf16x4*)(agg + (size_t)d * DIM + l32 * 4) = r;
}

// ---------------- fused GEMM, persistent + LDS double-buffer pipeline ----------
// out = A0bf@Wl.T + bias + bf16(A1)@Wr.T (+ReLU). Persistent blocks grid-stride
// 32-row tiles. A-tiles staged global->LDS via global_load_lds (6 calls/wave =
// 6KB in flight/wave), counted vmcnt(6) so next tile's loads stay in flight
// across the raw s_barrier. LDS chunk-XOR swizzle (chunk ^= row&7) applied on
// the GLOBAL source side (gl_lds writes linearly) and on the ds_read side.
#define GTILE   32
#define A0BYTES 8192            // 32 rows * 256B bf16
#define A1BYTES 16384           // 32 rows * 512B f32
#define LDSBUF  (A0BYTES + A1BYTES)

template <bool RELU>
__global__ __launch_bounds__(256, 3) void gemm_pipe(
    const bf16_t* __restrict__ A0, const float* __restrict__ A1,
    const bf16_t* __restrict__ Wc, const float* __restrict__ bias,
    float* __restrict__ out, int M) {
    __shared__ char smem[2 * LDSBUF];
    const int tid  = threadIdx.x;
    const int wid  = tid >> 6;
    const int lane = tid & 63;
    const int quad = lane >> 4;
    const int l16  = lane & 15;

    const int nt = (M + GTILE - 1) / GTILE;
    const int t0 = blockIdx.x;
    const int gs = gridDim.x;
    if (t0 >= nt) return;

    // B-slice resident in registers: breg[ct][kt] = 8 bf16 at k=kt*32+quad*8 of col wid*32+ct*16+l16
    bf16x8 breg[2][8];
#pragma unroll
    for (int ct = 0; ct < 2; ++ct)
#pragma unroll
        for (int kt = 0; kt < 8; ++kt)
            breg[ct][kt] = *(const bf16x8*)(
                Wc + (size_t)(wid * 32 + ct * 16 + l16) * 256 + kt * 32 + quad * 8);

    const float bcol0 = bias[wid * 32 + l16];
    const float bcol1 = bias[wid * 32 + 16 + l16];
    const int sw = l16 & 7;

    // tile-invariant staging decode (per lane): which (row, swizzled-src-chunk)
    int a0row[2], a0sc[2];      // A0: 2 wave-calls, elem offsets (bf16)
#pragma unroll
    for (int c = 0; c < 2; ++c) {
        int o  = wid * 2048 + c * 1024 + lane * 16;   // [0, 8192)
        int row = o >> 8;
        int ch  = (o >> 4) & 15;
        a0row[c] = row;
        a0sc[c]  = (ch ^ (row & 7)) * 8;
    }
    int a1row[4], a1sc[4];      // A1: 4 wave-calls, elem offsets (f32)
#pragma unroll
    for (int c = 0; c < 4; ++c) {
        int o  = wid * 4096 + c * 1024 + lane * 16;   // [0, 16384)
        int row = o >> 9;
        int ch  = (o >> 4) & 31;
        a1row[c] = row;
        a1sc[c]  = (ch ^ (row & 7)) * 4;
    }

    auto STAGE = [&](int b, int t) {
        const int r0 = t * GTILE;
        char* base = smem + b * LDSBUF;
#pragma unroll
        for (int c = 0; c < 2; ++c) {
            int grow = r0 + a0row[c]; if (grow >= M) grow = M - 1;
            gl_lds16(A0 + (size_t)grow * DIM + a0sc[c],
                     base + wid * 2048 + c * 1024);
        }
#pragma unroll
        for (int c = 0; c < 4; ++c) {
            int grow = r0 + a1row[c]; if (grow >= M) grow = M - 1;
            gl_lds16(A1 + (size_t)grow * DIM + a1sc[c],
                     base + A0BYTES + wid * 4096 + c * 1024);
        }
    };

    auto COMPUTE = [&](int b, int t) {
        const int r0 = t * GTILE;
        const char* a0base = smem + b * LDSBUF;
        const char* a1base = a0base + A0BYTES;
        f32x4 acc[2][2];
#pragma unroll
        for (int rt = 0; rt < 2; ++rt) {
            acc[rt][0] = (f32x4){0.f, 0.f, 0.f, 0.f};
            acc[rt][1] = (f32x4){0.f, 0.f, 0.f, 0.f};
        }
#pragma unroll
        for (int rt = 0; rt < 2; ++rt) {
            const int row = rt * 16 + l16;
            bf16x8 alo[4];
#pragma unroll
            for (int kt = 0; kt < 4; ++kt)
                alo[kt] = *(const bf16x8*)(a0base + row * 256 + ((kt * 4 + quad) ^ sw) * 16);
#pragma unroll
            for (int kt = 0; kt < 4; ++kt) {
                acc[rt][0] = __builtin_amdgcn_mfma_f32_16x16x32_bf16(alo[kt], breg[0][kt], acc[rt][0], 0, 0, 0);
                acc[rt][1] = __builtin_amdgcn_mfma_f32_16x16x32_bf16(alo[kt], breg[1][kt], acc[rt][1], 0, 0, 0);
            }
#pragma unroll
            for (int kt = 0; kt < 4; ++kt) {
                const int cc = kt * 8 + quad * 2;
                float4 x0 = *(const float4*)(a1base + row * 512 + ((cc)     ^ sw) * 16);
                float4 x1 = *(const float4*)(a1base + row * 512 + ((cc + 1) ^ sw) * 16);
                bf16x8 ah;
                ah[0] = (bf16_t)x0.x; ah[1] = (bf16_t)x0.y;
                ah[2] = (bf16_t)x0.z; ah[3] = (bf16_t)x0.w;
                ah[4] = (bf16_t)x1.x; ah[5] = (bf16_t)x1.y;
                ah[6] = (bf16_t)x1.z; ah[7] = (bf16_t)x1.w;
                acc[rt][0] = __builtin_amdgcn_mfma_f32_16x16x32_bf16(ah, breg[0][kt + 4], acc[rt][0], 0, 0, 0);
                acc[rt][1] = __builtin_amdgcn_mfma_f32_16x16x32_bf16(ah, breg[1][kt + 4], acc[rt][1], 0, 0, 0);
            }
        }
        // epilogue: C/D layout col = lane&15, row = quad*4 + reg
#pragma unroll
        for (int ct = 0; ct < 2; ++ct) {
            const int col = wid * 32 + ct * 16 + l16;
            const float bv = ct ? bcol1 : bcol0;
#pragma unroll
            for (int rt = 0; rt < 2; ++rt)
#pragma unroll
                for (int r = 0; r < 4; ++r) {
                    int row = r0 + rt * 16 + quad * 4 + r;
                    if (row < M) {
                        float v = acc[rt][ct][r] + bv;
                        if (RELU) v = fmaxf(v, 0.f);
                        out[(size_t)row * DIM + col] = v;
                    }
                }
        }
    };

    STAGE(0, t0);
    int bufi = 0;
    for (int t = t0; t < nt; t += gs, bufi ^= 1) {
        const int nxt = t + gs;
        if (nxt < nt) {
            STAGE(bufi ^ 1, nxt);
            asm volatile("s_waitcnt vmcnt(6)" ::: "memory");   // current tile staged; next 6 stay in flight
        } else {
            asm volatile("s_waitcnt vmcnt(0)" ::: "memory");
        }
        __builtin_amdgcn_s_barrier();          // all waves' quarters visible
        COMPUTE(bufi, t);
        __builtin_amdgcn_s_barrier();          // all waves done reading before next STAGE overwrites
        __builtin_amdgcn_sched_barrier(0);
    }
}

// ---------------- launch ----------------
extern "C" void kernel_launch(void* const* d_in, const int* in_sizes, int n_in,
                              void* d_out, int out_size, void* d_ws, size_t ws_size,
                              hipStream_t stream) {
    const float* x_m = (const float*)d_in[0];
    const float* x_t = (const float*)d_in[1];
    const float* Wl  = (const float*)d_in[2];
    const float* bl  = (const float*)d_in[3];
    const float* Wr  = (const float*)d_in[4];
    const int* e_mt  = (const int*)d_in[5];
    const int* e_tm  = (const int*)d_in[6];

    const int Mm = in_sizes[0] / DIM;     // 100000
    const int Mt = in_sizes[1] / DIM;     // 100000
    const int E  = in_sizes[5] / 2;       // 400000
    const int NBt = (Mt + 255) / 256;
    const int NBm = (Mm + 255) / 256;

    float* out_m = (float*)d_out;
    float* out_t = (float*)d_out + (size_t)Mm * DIM;

    char* ws = (char*)d_ws;
    size_t off = 0;
    auto alloc = [&](size_t bytes) -> void* {
        void* p = ws + off;
        off += (bytes + 255) & ~(size_t)255;
        return p;
    };
    float*  xm2    = (float*)alloc((size_t)Mm * DIM * 4);
    float*  xt2    = (float*)alloc((size_t)Mt * DIM * 4);
    bf16_t* agg    = (bf16_t*)alloc((size_t)((Mm > Mt) ? Mm : Mt) * DIM * 2);
    int*    cnt_t  = (int*)alloc((size_t)Mt * 4);
    int*    cnt_m  = (int*)alloc((size_t)Mm * 4);
    int*    rs_t   = (int*)alloc((size_t)Mt * 4);
    int*    rs_m   = (int*)alloc((size_t)Mm * 4);
    int*    cur_tb = (int*)alloc((size_t)Mt * 4);
    int*    cur_mb = (int*)alloc((size_t)Mm * 4);
    int*    partial= (int*)alloc((size_t)((Mm > Mt) ? Mm : Mt) * 4);
    int*    bsum   = (int*)alloc((size_t)((NBt > NBm) ? NBt : NBm) * 4);
    int*    csr_t  = (int*)alloc((size_t)E * 4);
    int*    csr_m  = (int*)alloc((size_t)E * 4);
    bf16_t* Wc     = (bf16_t*)alloc((size_t)6 * 128 * 256 * 2);

    // ---- per-launch structure prep ----
    hipMemsetAsync(cnt_t, 0, (size_t)Mt * 4, stream);
    hipMemsetAsync(cnt_m, 0, (size_t)Mm * 4, stream);
    prep_weights<<<(6 * 128 * 256 + 255) / 256, 256, 0, stream>>>(Wl, Wr, Wc);
    count_edges2<<<(2 * E + 255) / 256, 256, 0, stream>>>(e_mt + E, cnt_t, e_tm + E, cnt_m, E);

    // CSR offsets for edge_mt (dst = track)
    scan_local<<<NBt, 256, 0, stream>>>(cnt_t, partial, bsum, Mt);
    scan_blocks<<<1, 256, 0, stream>>>(bsum, NBt);
    add_offsets<<<NBt, 256, 0, stream>>>(partial, bsum, rs_t, cur_tb, Mt);

    // CSR offsets for edge_tm (dst = musician)
    scan_local<<<NBm, 256, 0, stream>>>(cnt_m, partial, bsum, Mm);
    scan_blocks<<<1, 256, 0, stream>>>(bsum, NBm);
    add_offsets<<<NBm, 256, 0, stream>>>(partial, bsum, rs_m, cur_mb, Mm);

    bin_edges2<<<(2 * E + 255) / 256, 256, 0, stream>>>(e_mt, e_mt + E, cur_tb, csr_t,
                                                        e_tm, e_tm + E, cur_mb, csr_m, E);

    const int gwT = ((Mt + 1) / 2 + 3) / 4;   // gather: 2 rows/wave, 4 waves/block
    const int gwM = ((Mm + 1) / 2 + 3) / 4;
    int ggT = 768, ggM = 768;                 // 3 blocks/CU * 256 CUs, persistent
    {
        int ntT = (Mt + GTILE - 1) / GTILE, ntM = (Mm + GTILE - 1) / GTILE;
        if (ggT > ntT) ggT = ntT;
        if (ggM > ntM) ggM = ntM;
    }

    const float* cm = x_m;
    const float* ct = x_t;
    for (int layer = 0; layer < 3; ++layer) {
        float *nxt_m, *nxt_t;
        if (layer == 1) { nxt_m = xm2;   nxt_t = xt2;   }
        else            { nxt_m = out_m; nxt_t = out_t; }
        const float* biasT = bl + ((size_t)layer * 2 + 0) * DIM;
        const float* biasM = bl + ((size_t)layer * 2 + 1) * DIM;
        const bf16_t* WcT = Wc + ((size_t)layer * 2 + 0) * 128 * 256;
        const bf16_t* WcM = Wc + ((size_t)layer * 2 + 1) * 128 * 256;

        // edge type 0: musician -> track (dst = track)
        gather_mean_bf16<<<gwT, 256, 0, stream>>>(cm, rs_t, cnt_t, csr_t, agg, Mt);
        if (layer < 2)
            gemm_pipe<true ><<<ggT, 256, 0, stream>>>(agg, ct, WcT, biasT, nxt_t, Mt);
        else
            gemm_pipe<false><<<ggT, 256, 0, stream>>>(agg, ct, WcT, biasT, nxt_t, Mt);

        // edge type 1: track -> musician (dst = musician)
        gather_mean_bf16<<<gwM, 256, 0, stream>>>(ct, rs_m, cnt_m, csr_m, agg, Mm);
        if (layer < 2)
            gemm_pipe<true ><<<ggM, 256, 0, stream>>>(agg, cm, WcM, biasM, nxt_m, Mm);
        else
            gemm_pipe<false><<<ggM, 256, 0, stream>>>(agg, cm, WcM, biasM, nxt_m, Mm);

        cm = nxt_m;
        ct = nxt_t;
    }
}

// Round 3
// 594.491 us; speedup vs baseline: 1.3907x; 1.0204x over previous
//
#include <hip/hip_runtime.h>
#include <hip/hip_bf16.h>

typedef __bf16 bf16_t;
typedef __attribute__((ext_vector_type(4))) __bf16 bf16x4;
typedef __attribute__((ext_vector_type(8))) __bf16 bf16x8;
typedef __attribute__((ext_vector_type(4))) float f32x4;

#define DIM 128

// async global->LDS, 16B per lane. LDS dest = wave-uniform base + lane*16.
__device__ __forceinline__ void gl_lds16(const void* g, void* l) {
    __builtin_amdgcn_global_load_lds(
        (const __attribute__((address_space(1))) unsigned int*)g,
        (__attribute__((address_space(3))) unsigned int*)l, 16, 0, 0);
}

// ---------------- weight prep: Wc[s][n][k256] bf16, s = layer*2 + type ----------
__global__ void prep_weights(const float* __restrict__ Wl, const float* __restrict__ Wr,
                             bf16_t* __restrict__ Wc) {
    int idx = blockIdx.x * blockDim.x + threadIdx.x;   // over 6*128*256
    if (idx >= 6 * 128 * 256) return;
    int k = idx & 255;
    int n = (idx >> 8) & 127;
    int s = idx >> 15;                                  // 0..5
    float v;
    if (k < 128) v = Wl[((size_t)s * 128 + n) * 128 + k];
    else         v = Wr[((size_t)s * 128 + n) * 128 + (k - 128)];
    Wc[idx] = (bf16_t)v;
}

// ---------------- degree count (both edge types in one launch) ----------------
__global__ void count_edges2(const int* __restrict__ dA, int* __restrict__ cA,
                             const int* __restrict__ dB, int* __restrict__ cB, int E) {
    int i = blockIdx.x * blockDim.x + threadIdx.x;
    if (i < E) atomicAdd(&cA[dA[i]], 1);
    else if (i < 2 * E) atomicAdd(&cB[dB[i - E]], 1);
}

// ---------------- CSR build: block scan ----------------
__global__ __launch_bounds__(256) void scan_local(const int* __restrict__ cnt,
                                                  int* __restrict__ partial,
                                                  int* __restrict__ blocksum, int M) {
    __shared__ int sdata[256];
    int i = blockIdx.x * 256 + threadIdx.x;
    int v = (i < M) ? cnt[i] : 0;
    sdata[threadIdx.x] = v;
    __syncthreads();
    for (int off = 1; off < 256; off <<= 1) {
        int t = (threadIdx.x >= off) ? sdata[threadIdx.x - off] : 0;
        __syncthreads();
        sdata[threadIdx.x] += t;
        __syncthreads();
    }
    int incl = sdata[threadIdx.x];
    if (i < M) partial[i] = incl - v;
    if (threadIdx.x == 255) blocksum[blockIdx.x] = incl;
}

__global__ __launch_bounds__(256) void scan_blocks(int* __restrict__ blocksum, int NB) {
    __shared__ int sdata[256];
    __shared__ int running;
    if (threadIdx.x == 0) running = 0;
    __syncthreads();
    for (int base = 0; base < NB; base += 256) {
        int i = base + threadIdx.x;
        int v = (i < NB) ? blocksum[i] : 0;
        sdata[threadIdx.x] = v;
        __syncthreads();
        for (int off = 1; off < 256; off <<= 1) {
            int t = (threadIdx.x >= off) ? sdata[threadIdx.x - off] : 0;
            __syncthreads();
            sdata[threadIdx.x] += t;
            __syncthreads();
        }
        int incl = sdata[threadIdx.x];
        int r = running;
        __syncthreads();
        if (i < NB) blocksum[i] = incl - v + r;
        if (threadIdx.x == 0) running = r + sdata[255];
        __syncthreads();
    }
}

__global__ void add_offsets(const int* __restrict__ partial, const int* __restrict__ blocksum,
                            int* __restrict__ rowstart, int* __restrict__ cursor, int M) {
    int i = blockIdx.x * blockDim.x + threadIdx.x;
    if (i < M) {
        int rs = partial[i] + blocksum[i >> 8];
        rowstart[i] = rs;
        cursor[i] = rs;
    }
}

__global__ void bin_edges2(const int* __restrict__ sA, const int* __restrict__ dA,
                           int* __restrict__ curA, int* __restrict__ csrA,
                           const int* __restrict__ sB, const int* __restrict__ dB,
                           int* __restrict__ curB, int* __restrict__ csrB, int E) {
    int e = blockIdx.x * blockDim.x + threadIdx.x;
    if (e < E) {
        int d = dA[e];
        int pos = atomicAdd(&curA[d], 1);
        csrA[pos] = sA[e];
    } else if (e < 2 * E) {
        int i = e - E;
        int d = dB[i];
        int pos = atomicAdd(&curB[d], 1);
        csrB[pos] = sB[i];
    }
}

// ---------------- merged gather-mean -> bf16, sides interleaved per wave --------
// Even waves do side A, odd waves side B; each wave does 2 dst rows (half-wave
// each, 32 lanes x float4 = one 128-f32 row).
__global__ __launch_bounds__(256) void gather2(
    const float* __restrict__ xsA, const int* __restrict__ rsA,
    const int* __restrict__ cnA, const int* __restrict__ csA,
    bf16_t* __restrict__ agA, int MA,
    const float* __restrict__ xsB, const int* __restrict__ rsB,
    const int* __restrict__ cnB, const int* __restrict__ csB,
    bf16_t* __restrict__ agB, int MB) {
    int gw   = (blockIdx.x * 256 + threadIdx.x) >> 6;
    int lane = threadIdx.x & 63;
    int half = lane >> 5;
    int l32  = lane & 31;
    int side = gw & 1;
    int d    = (gw >> 1) * 2 + half;
    const float* xs; const int *rs, *cn, *cs; bf16_t* ag; int M;
    if (side == 0) { xs = xsA; rs = rsA; cn = cnA; cs = csA; ag = agA; M = MA; }
    else           { xs = xsB; rs = rsB; cn = cnB; cs = csB; ag = agB; M = MB; }
    if (d >= M) return;

    int start = rs[d];
    int n = cn[d];
    float4 acc0 = {0.f, 0.f, 0.f, 0.f};
    float4 acc1 = {0.f, 0.f, 0.f, 0.f};
    int k = 0;
    for (; k + 1 < n; k += 2) {
        int s0 = cs[start + k];
        int s1 = cs[start + k + 1];
        float4 v0 = ((const float4*)(xs + (size_t)s0 * DIM))[l32];
        float4 v1 = ((const float4*)(xs + (size_t)s1 * DIM))[l32];
        acc0.x += v0.x; acc0.y += v0.y; acc0.z += v0.z; acc0.w += v0.w;
        acc1.x += v1.x; acc1.y += v1.y; acc1.z += v1.z; acc1.w += v1.w;
    }
    if (k < n) {
        int s = cs[start + k];
        float4 v = ((const float4*)(xs + (size_t)s * DIM))[l32];
        acc0.x += v.x; acc0.y += v.y; acc0.z += v.z; acc0.w += v.w;
    }
    float invn = 1.0f / (float)max(n, 1);
    bf16x4 r;
    r[0] = (bf16_t)((acc0.x + acc1.x) * invn);
    r[1] = (bf16_t)((acc0.y + acc1.y) * invn);
    r[2] = (bf16_t)((acc0.z + acc1.z) * invn);
    r[3] = (bf16_t)((acc0.w + acc1.w) * invn);
    *(bf16x4*)(ag + (size_t)d * DIM + l32 * 4) = r;
}

// ---------------- merged fused GEMM, persistent + LDS double-buffer pipeline ----
// out = A0bf@Wl.T + bias + bf16(A1)@Wr.T (+ReLU), both per-layer GEMMs in one
// dispatch. Even blocks side A, odd blocks side B; each side's blocks persist
// and grid-stride 32-row tiles (total grid 768 = full residency at 3 blk/CU,
// so both sides are co-resident). A-tiles staged global->LDS via
// global_load_lds (6 calls/wave), counted vmcnt(6) keeps next tile's loads in
// flight across the raw s_barrier. LDS chunk-XOR swizzle (chunk ^= row&7)
// applied on the GLOBAL source side and on the ds_read side.
#define GTILE   32
#define A0BYTES 8192            // 32 rows * 256B bf16
#define A1BYTES 16384           // 32 rows * 512B f32
#define LDSBUF  (A0BYTES + A1BYTES)

template <bool RELU>
__global__ __launch_bounds__(256, 3) void gemm2(
    const bf16_t* __restrict__ A0a, const float* __restrict__ A1a,
    const bf16_t* __restrict__ Wca, const float* __restrict__ ba,
    float* __restrict__ oa, int Ma,
    const bf16_t* __restrict__ A0b, const float* __restrict__ A1b,
    const bf16_t* __restrict__ Wcb, const float* __restrict__ bb,
    float* __restrict__ ob, int Mb) {
    __shared__ char smem[2 * LDSBUF];
    const int tid  = threadIdx.x;
    const int wid  = tid >> 6;
    const int lane = tid & 63;
    const int quad = lane >> 4;
    const int l16  = lane & 15;

    const int side = blockIdx.x & 1;
    const int t0   = blockIdx.x >> 1;
    const int gs   = gridDim.x >> 1;       // host guarantees even grid

    const bf16_t* A0; const float* A1; const bf16_t* Wc; const float* bias; float* out; int M;
    if (side == 0) { A0 = A0a; A1 = A1a; Wc = Wca; bias = ba; out = oa; M = Ma; }
    else           { A0 = A0b; A1 = A1b; Wc = Wcb; bias = bb; out = ob; M = Mb; }
    const int nt = (M + GTILE - 1) / GTILE;
    if (t0 >= nt) return;

    // B-slice resident in registers: breg[ct][kt] = 8 bf16 at k=kt*32+quad*8 of col wid*32+ct*16+l16
    bf16x8 breg[2][8];
#pragma unroll
    for (int ct = 0; ct < 2; ++ct)
#pragma unroll
        for (int kt = 0; kt < 8; ++kt)
            breg[ct][kt] = *(const bf16x8*)(
                Wc + (size_t)(wid * 32 + ct * 16 + l16) * 256 + kt * 32 + quad * 8);

    const float bcol0 = bias[wid * 32 + l16];
    const float bcol1 = bias[wid * 32 + 16 + l16];
    const int sw = l16 & 7;

    // tile-invariant staging decode (per lane): which (row, swizzled-src-chunk)
    int a0row[2], a0sc[2];      // A0: 2 wave-calls, elem offsets (bf16)
#pragma unroll
    for (int c = 0; c < 2; ++c) {
        int o  = wid * 2048 + c * 1024 + lane * 16;   // [0, 8192)
        int row = o >> 8;
        int ch  = (o >> 4) & 15;
        a0row[c] = row;
        a0sc[c]  = (ch ^ (row & 7)) * 8;
    }
    int a1row[4], a1sc[4];      // A1: 4 wave-calls, elem offsets (f32)
#pragma unroll
    for (int c = 0; c < 4; ++c) {
        int o  = wid * 4096 + c * 1024 + lane * 16;   // [0, 16384)
        int row = o >> 9;
        int ch  = (o >> 4) & 31;
        a1row[c] = row;
        a1sc[c]  = (ch ^ (row & 7)) * 4;
    }

    auto STAGE = [&](int b, int t) {
        const int r0 = t * GTILE;
        char* base = smem + b * LDSBUF;
#pragma unroll
        for (int c = 0; c < 2; ++c) {
            int grow = r0 + a0row[c]; if (grow >= M) grow = M - 1;
            gl_lds16(A0 + (size_t)grow * DIM + a0sc[c],
                     base + wid * 2048 + c * 1024);
        }
#pragma unroll
        for (int c = 0; c < 4; ++c) {
            int grow = r0 + a1row[c]; if (grow >= M) grow = M - 1;
            gl_lds16(A1 + (size_t)grow * DIM + a1sc[c],
                     base + A0BYTES + wid * 4096 + c * 1024);
        }
    };

    auto COMPUTE = [&](int b, int t) {
        const int r0 = t * GTILE;
        const char* a0base = smem + b * LDSBUF;
        const char* a1base = a0base + A0BYTES;
        f32x4 acc[2][2];
#pragma unroll
        for (int rt = 0; rt < 2; ++rt) {
            acc[rt][0] = (f32x4){0.f, 0.f, 0.f, 0.f};
            acc[rt][1] = (f32x4){0.f, 0.f, 0.f, 0.f};
        }
#pragma unroll
        for (int rt = 0; rt < 2; ++rt) {
            const int row = rt * 16 + l16;
            bf16x8 alo[4];
#pragma unroll
            for (int kt = 0; kt < 4; ++kt)
                alo[kt] = *(const bf16x8*)(a0base + row * 256 + ((kt * 4 + quad) ^ sw) * 16);
#pragma unroll
            for (int kt = 0; kt < 4; ++kt) {
                acc[rt][0] = __builtin_amdgcn_mfma_f32_16x16x32_bf16(alo[kt], breg[0][kt], acc[rt][0], 0, 0, 0);
                acc[rt][1] = __builtin_amdgcn_mfma_f32_16x16x32_bf16(alo[kt], breg[1][kt], acc[rt][1], 0, 0, 0);
            }
#pragma unroll
            for (int kt = 0; kt < 4; ++kt) {
                const int cc = kt * 8 + quad * 2;
                float4 x0 = *(const float4*)(a1base + row * 512 + ((cc)     ^ sw) * 16);
                float4 x1 = *(const float4*)(a1base + row * 512 + ((cc + 1) ^ sw) * 16);
                bf16x8 ah;
                ah[0] = (bf16_t)x0.x; ah[1] = (bf16_t)x0.y;
                ah[2] = (bf16_t)x0.z; ah[3] = (bf16_t)x0.w;
                ah[4] = (bf16_t)x1.x; ah[5] = (bf16_t)x1.y;
                ah[6] = (bf16_t)x1.z; ah[7] = (bf16_t)x1.w;
                acc[rt][0] = __builtin_amdgcn_mfma_f32_16x16x32_bf16(ah, breg[0][kt + 4], acc[rt][0], 0, 0, 0);
                acc[rt][1] = __builtin_amdgcn_mfma_f32_16x16x32_bf16(ah, breg[1][kt + 4], acc[rt][1], 0, 0, 0);
            }
        }
        // epilogue: C/D layout col = lane&15, row = quad*4 + reg
#pragma unroll
        for (int ct = 0; ct < 2; ++ct) {
            const int col = wid * 32 + ct * 16 + l16;
            const float bv = ct ? bcol1 : bcol0;
#pragma unroll
            for (int rt = 0; rt < 2; ++rt)
#pragma unroll
                for (int r = 0; r < 4; ++r) {
                    int row = r0 + rt * 16 + quad * 4 + r;
                    if (row < M) {
                        float v = acc[rt][ct][r] + bv;
                        if (RELU) v = fmaxf(v, 0.f);
                        out[(size_t)row * DIM + col] = v;
                    }
                }
        }
    };

    STAGE(0, t0);
    int bufi = 0;
    for (int t = t0; t < nt; t += gs, bufi ^= 1) {
        const int nxt = t + gs;
        if (nxt < nt) {
            STAGE(bufi ^ 1, nxt);
            asm volatile("s_waitcnt vmcnt(6)" ::: "memory");   // current tile staged; next 6 stay in flight
        } else {
            asm volatile("s_waitcnt vmcnt(0)" ::: "memory");
        }
        __builtin_amdgcn_s_barrier();          // all waves' quarters visible
        COMPUTE(bufi, t);
        __builtin_amdgcn_s_barrier();          // all waves done reading before next STAGE overwrites
        __builtin_amdgcn_sched_barrier(0);
    }
}

// ---------------- launch ----------------
extern "C" void kernel_launch(void* const* d_in, const int* in_sizes, int n_in,
                              void* d_out, int out_size, void* d_ws, size_t ws_size,
                              hipStream_t stream) {
    const float* x_m = (const float*)d_in[0];
    const float* x_t = (const float*)d_in[1];
    const float* Wl  = (const float*)d_in[2];
    const float* bl  = (const float*)d_in[3];
    const float* Wr  = (const float*)d_in[4];
    const int* e_mt  = (const int*)d_in[5];
    const int* e_tm  = (const int*)d_in[6];

    const int Mm = in_sizes[0] / DIM;     // 100000
    const int Mt = in_sizes[1] / DIM;     // 100000
    const int E  = in_sizes[5] / 2;       // 400000
    const int NBt = (Mt + 255) / 256;
    const int NBm = (Mm + 255) / 256;

    float* out_m = (float*)d_out;
    float* out_t = (float*)d_out + (size_t)Mm * DIM;

    char* ws = (char*)d_ws;
    size_t off = 0;
    auto alloc = [&](size_t bytes) -> void* {
        void* p = ws + off;
        off += (bytes + 255) & ~(size_t)255;
        return p;
    };
    float*  xm2    = (float*)alloc((size_t)Mm * DIM * 4);
    float*  xt2    = (float*)alloc((size_t)Mt * DIM * 4);
    bf16_t* aggT   = (bf16_t*)alloc((size_t)Mt * DIM * 2);
    bf16_t* aggM   = (bf16_t*)alloc((size_t)Mm * DIM * 2);
    int*    cnt_t  = (int*)alloc((size_t)Mt * 4);
    int*    cnt_m  = (int*)alloc((size_t)Mm * 4);
    int*    rs_t   = (int*)alloc((size_t)Mt * 4);
    int*    rs_m   = (int*)alloc((size_t)Mm * 4);
    int*    cur_tb = (int*)alloc((size_t)Mt * 4);
    int*    cur_mb = (int*)alloc((size_t)Mm * 4);
    int*    partial= (int*)alloc((size_t)((Mm > Mt) ? Mm : Mt) * 4);
    int*    bsum   = (int*)alloc((size_t)((NBt > NBm) ? NBt : NBm) * 4);
    int*    csr_t  = (int*)alloc((size_t)E * 4);
    int*    csr_m  = (int*)alloc((size_t)E * 4);
    bf16_t* Wc     = (bf16_t*)alloc((size_t)6 * 128 * 256 * 2);

    // ---- per-launch structure prep ----
    hipMemsetAsync(cnt_t, 0, (size_t)Mt * 4, stream);
    hipMemsetAsync(cnt_m, 0, (size_t)Mm * 4, stream);
    prep_weights<<<(6 * 128 * 256 + 255) / 256, 256, 0, stream>>>(Wl, Wr, Wc);
    count_edges2<<<(2 * E + 255) / 256, 256, 0, stream>>>(e_mt + E, cnt_t, e_tm + E, cnt_m, E);

    // CSR offsets for edge_mt (dst = track)
    scan_local<<<NBt, 256, 0, stream>>>(cnt_t, partial, bsum, Mt);
    scan_blocks<<<1, 256, 0, stream>>>(bsum, NBt);
    add_offsets<<<NBt, 256, 0, stream>>>(partial, bsum, rs_t, cur_tb, Mt);

    // CSR offsets for edge_tm (dst = musician)
    scan_local<<<NBm, 256, 0, stream>>>(cnt_m, partial, bsum, Mm);
    scan_blocks<<<1, 256, 0, stream>>>(bsum, NBm);
    add_offsets<<<NBm, 256, 0, stream>>>(partial, bsum, rs_m, cur_mb, Mm);

    bin_edges2<<<(2 * E + 255) / 256, 256, 0, stream>>>(e_mt, e_mt + E, cur_tb, csr_t,
                                                        e_tm, e_tm + E, cur_mb, csr_m, E);

    // merged gather grid: interleaved sides, 2 rows per wave, 4 waves/block
    const int wT = (Mt + 1) / 2, wM = (Mm + 1) / 2;
    const int gwaves = 2 * ((wT > wM) ? wT : wM);
    const int gblocks = (gwaves + 3) / 4;

    // merged gemm grid: even, full residency (3 blk/CU x 256 CU)
    int GG = 768;
    {
        int ntT = (Mt + GTILE - 1) / GTILE, ntM = (Mm + GTILE - 1) / GTILE;
        int need = 2 * ((ntT > ntM) ? ntT : ntM);
        if (GG > need) GG = need;
        GG &= ~1;
        if (GG < 2) GG = 2;
    }

    const float* cm = x_m;
    const float* ct = x_t;
    for (int layer = 0; layer < 3; ++layer) {
        float *nxt_m, *nxt_t;
        if (layer == 1) { nxt_m = xm2;   nxt_t = xt2;   }
        else            { nxt_m = out_m; nxt_t = out_t; }
        const float* biasT = bl + ((size_t)layer * 2 + 0) * DIM;
        const float* biasM = bl + ((size_t)layer * 2 + 1) * DIM;
        const bf16_t* WcT = Wc + ((size_t)layer * 2 + 0) * 128 * 256;
        const bf16_t* WcM = Wc + ((size_t)layer * 2 + 1) * 128 * 256;

        // both aggregations in one dispatch (sides interleaved per wave)
        gather2<<<gblocks, 256, 0, stream>>>(cm, rs_t, cnt_t, csr_t, aggT, Mt,
                                             ct, rs_m, cnt_m, csr_m, aggM, Mm);
        // both GEMMs in one persistent dispatch (sides interleaved per block)
        if (layer < 2)
            gemm2<true ><<<GG, 256, 0, stream>>>(aggT, ct, WcT, biasT, nxt_t, Mt,
                                                 aggM, cm, WcM, biasM, nxt_m, Mm);
        else
            gemm2<false><<<GG, 256, 0, stream>>>(aggT, ct, WcT, biasT, nxt_t, Mt,
                                                 aggM, cm, WcM, biasM, nxt_m, Mm);

        cm = nxt_m;
        ct = nxt_t;
    }
}

// Round 4
// 567.157 us; speedup vs baseline: 1.4578x; 1.0482x over previous
//
#include <hip/hip_runtime.h>
#include <hip/hip_bf16.h>

typedef __bf16 bf16_t;
typedef __attribute__((ext_vector_type(4))) __bf16 bf16x4;
typedef __attribute__((ext_vector_type(8))) __bf16 bf16x8;
typedef __attribute__((ext_vector_type(4))) float f32x4;

#define DIM 128

// async global->LDS, 16B per lane. LDS dest = wave-uniform base + lane*16.
__device__ __forceinline__ void gl_lds16(const void* g, void* l) {
    __builtin_amdgcn_global_load_lds(
        (const __attribute__((address_space(1))) unsigned int*)g,
        (__attribute__((address_space(3))) unsigned int*)l, 16, 0, 0);
}

// ------------- merged weight-prep + degree count (independent work) -------------
// blocks [0, PB): Wc[s][n][k256] bf16 from Wl/Wr.  blocks [PB, ...): count edges.
__global__ void prep_count(const float* __restrict__ Wl, const float* __restrict__ Wr,
                           bf16_t* __restrict__ Wc,
                           const int* __restrict__ dA, int* __restrict__ cA,
                           const int* __restrict__ dB, int* __restrict__ cB,
                           int E, int PB) {
    int blk = blockIdx.x;
    if (blk < PB) {
        int idx = blk * 256 + threadIdx.x;           // over 6*128*256
        if (idx >= 6 * 128 * 256) return;
        int k = idx & 255;
        int n = (idx >> 8) & 127;
        int s = idx >> 15;                            // 0..5
        float v;
        if (k < 128) v = Wl[((size_t)s * 128 + n) * 128 + k];
        else         v = Wr[((size_t)s * 128 + n) * 128 + (k - 128)];
        Wc[idx] = (bf16_t)v;
    } else {
        int i = (blk - PB) * 256 + threadIdx.x;
        if (i < E) atomicAdd(&cA[dA[i]], 1);
        else if (i < 2 * E) atomicAdd(&cB[dB[i - E]], 1);
    }
}

// ---------------- CSR build: both sides in each scan stage ----------------
__global__ __launch_bounds__(256) void scan_local2(
    const int* __restrict__ cntA, int* __restrict__ partA, int* __restrict__ bsumA,
    int MA, int NBA,
    const int* __restrict__ cntB, int* __restrict__ partB, int* __restrict__ bsumB,
    int MB) {
    int blk = blockIdx.x;
    const int* cnt; int* partial; int* blocksum; int M; int b;
    if (blk < NBA) { cnt = cntA; partial = partA; blocksum = bsumA; M = MA; b = blk; }
    else           { cnt = cntB; partial = partB; blocksum = bsumB; M = MB; b = blk - NBA; }
    __shared__ int sdata[256];
    int i = b * 256 + threadIdx.x;
    int v = (i < M) ? cnt[i] : 0;
    sdata[threadIdx.x] = v;
    __syncthreads();
    for (int off = 1; off < 256; off <<= 1) {
        int t = (threadIdx.x >= off) ? sdata[threadIdx.x - off] : 0;
        __syncthreads();
        sdata[threadIdx.x] += t;
        __syncthreads();
    }
    int incl = sdata[threadIdx.x];
    if (i < M) partial[i] = incl - v;
    if (threadIdx.x == 255) blocksum[b] = incl;
}

__global__ __launch_bounds__(256) void scan_blocks2(int* __restrict__ bsA, int NA,
                                                    int* __restrict__ bsB, int NBcnt) {
    int* blocksum = blockIdx.x ? bsB : bsA;
    int NB = blockIdx.x ? NBcnt : NA;
    __shared__ int sdata[256];
    __shared__ int running;
    if (threadIdx.x == 0) running = 0;
    __syncthreads();
    for (int base = 0; base < NB; base += 256) {
        int i = base + threadIdx.x;
        int v = (i < NB) ? blocksum[i] : 0;
        sdata[threadIdx.x] = v;
        __syncthreads();
        for (int off = 1; off < 256; off <<= 1) {
            int t = (threadIdx.x >= off) ? sdata[threadIdx.x - off] : 0;
            __syncthreads();
            sdata[threadIdx.x] += t;
            __syncthreads();
        }
        int incl = sdata[threadIdx.x];
        int r = running;
        __syncthreads();
        if (i < NB) blocksum[i] = incl - v + r;
        if (threadIdx.x == 0) running = r + sdata[255];
        __syncthreads();
    }
}

__global__ __launch_bounds__(256) void add_offsets2(
    const int* __restrict__ pA, const int* __restrict__ bsA,
    int* __restrict__ rsA, int* __restrict__ curA, int MA, int NBA,
    const int* __restrict__ pB, const int* __restrict__ bsB,
    int* __restrict__ rsB, int* __restrict__ curB, int MB) {
    int blk = blockIdx.x;
    const int *partial, *blocksum; int *rowstart, *cursor; int M, b;
    if (blk < NBA) { partial = pA; blocksum = bsA; rowstart = rsA; cursor = curA; M = MA; b = blk; }
    else           { partial = pB; blocksum = bsB; rowstart = rsB; cursor = curB; M = MB; b = blk - NBA; }
    int i = b * 256 + threadIdx.x;
    if (i < M) {
        int rs = partial[i] + blocksum[i >> 8];
        rowstart[i] = rs;
        cursor[i] = rs;
    }
}

__global__ void bin_edges2(const int* __restrict__ sA, const int* __restrict__ dA,
                           int* __restrict__ curA, int* __restrict__ csrA,
                           const int* __restrict__ sB, const int* __restrict__ dB,
                           int* __restrict__ curB, int* __restrict__ csrB, int E) {
    int e = blockIdx.x * blockDim.x + threadIdx.x;
    if (e < E) {
        int d = dA[e];
        int pos = atomicAdd(&curA[d], 1);
        csrA[pos] = sA[e];
    } else if (e < 2 * E) {
        int i = e - E;
        int d = dB[i];
        int pos = atomicAdd(&curB[d], 1);
        csrB[pos] = sB[i];
    }
}

// ---------------- merged gather-mean -> bf16, sides interleaved per wave --------
// Even waves side A, odd waves side B. Each half-wave owns one dst row (32 lanes
// x float4 = one 128-f32 row). Edges processed in batches of 8: all 8 csr-index
// loads issued, then all 8 row loads (tail clamps to last edge; duplicate loads
// hit L1, no extra HBM traffic), then weighted accumulate. Parity split
// (even j -> acc0, odd j -> acc1, ascending) preserves the exact summation
// order of the previous 2-unrolled version -> bit-identical results.
__global__ __launch_bounds__(256) void gather2(
    const float* __restrict__ xsA, const int* __restrict__ rsA,
    const int* __restrict__ cnA, const int* __restrict__ csA,
    bf16_t* __restrict__ agA, int MA,
    const float* __restrict__ xsB, const int* __restrict__ rsB,
    const int* __restrict__ cnB, const int* __restrict__ csB,
    bf16_t* __restrict__ agB, int MB) {
    int gw   = (blockIdx.x * 256 + threadIdx.x) >> 6;
    int lane = threadIdx.x & 63;
    int half = lane >> 5;
    int l32  = lane & 31;
    int side = gw & 1;
    int d    = (gw >> 1) * 2 + half;
    const float* xs; const int *rs, *cn, *cs; bf16_t* ag; int M;
    if (side == 0) { xs = xsA; rs = rsA; cn = cnA; cs = csA; ag = agA; M = MA; }
    else           { xs = xsB; rs = rsB; cn = cnB; cs = csB; ag = agB; M = MB; }
    if (d >= M) return;

    int start = rs[d];
    int n = cn[d];
    float4 acc0 = {0.f, 0.f, 0.f, 0.f};
    float4 acc1 = {0.f, 0.f, 0.f, 0.f};
    for (int k = 0; k < n; k += 8) {
        int sv[8];
#pragma unroll
        for (int j = 0; j < 8; ++j) {
            int kk = k + j;
            sv[j] = cs[start + min(kk, n - 1)];
        }
        float4 vv[8];
#pragma unroll
        for (int j = 0; j < 8; ++j)
            vv[j] = ((const float4*)(xs + (size_t)sv[j] * DIM))[l32];
#pragma unroll
        for (int j = 0; j < 8; j += 2) {
            float w0 = (k + j     < n) ? 1.f : 0.f;
            float w1 = (k + j + 1 < n) ? 1.f : 0.f;
            acc0.x += vv[j].x * w0; acc0.y += vv[j].y * w0;
            acc0.z += vv[j].z * w0; acc0.w += vv[j].w * w0;
            acc1.x += vv[j + 1].x * w1; acc1.y += vv[j + 1].y * w1;
            acc1.z += vv[j + 1].z * w1; acc1.w += vv[j + 1].w * w1;
        }
    }
    float invn = 1.0f / (float)max(n, 1);
    bf16x4 r;
    r[0] = (bf16_t)((acc0.x + acc1.x) * invn);
    r[1] = (bf16_t)((acc0.y + acc1.y) * invn);
    r[2] = (bf16_t)((acc0.z + acc1.z) * invn);
    r[3] = (bf16_t)((acc0.w + acc1.w) * invn);
    *(bf16x4*)(ag + (size_t)d * DIM + l32 * 4) = r;
}

// ---------------- merged fused GEMM, persistent + LDS double-buffer pipeline ----
// out = A0bf@Wl.T + bias + bf16(A1)@Wr.T (+ReLU), both per-layer GEMMs in one
// dispatch. Even blocks side A, odd blocks side B; each side's blocks persist
// and grid-stride 32-row tiles. A-tiles staged global->LDS via global_load_lds
// (6 calls/wave), counted vmcnt(6) keeps next tile's loads in flight across the
// raw s_barrier. LDS chunk-XOR swizzle (chunk ^= row&7) applied on the GLOBAL
// source side and on the ds_read side.
#define GTILE   32
#define A0BYTES 8192            // 32 rows * 256B bf16
#define A1BYTES 16384           // 32 rows * 512B f32
#define LDSBUF  (A0BYTES + A1BYTES)

template <bool RELU>
__global__ __launch_bounds__(256, 3) void gemm2(
    const bf16_t* __restrict__ A0a, const float* __restrict__ A1a,
    const bf16_t* __restrict__ Wca, const float* __restrict__ ba,
    float* __restrict__ oa, int Ma,
    const bf16_t* __restrict__ A0b, const float* __restrict__ A1b,
    const bf16_t* __restrict__ Wcb, const float* __restrict__ bb,
    float* __restrict__ ob, int Mb) {
    __shared__ char smem[2 * LDSBUF];
    const int tid  = threadIdx.x;
    const int wid  = tid >> 6;
    const int lane = tid & 63;
    const int quad = lane >> 4;
    const int l16  = lane & 15;

    const int side = blockIdx.x & 1;
    const int t0   = blockIdx.x >> 1;
    const int gs   = gridDim.x >> 1;       // host guarantees even grid

    const bf16_t* A0; const float* A1; const bf16_t* Wc; const float* bias; float* out; int M;
    if (side == 0) { A0 = A0a; A1 = A1a; Wc = Wca; bias = ba; out = oa; M = Ma; }
    else           { A0 = A0b; A1 = A1b; Wc = Wcb; bias = bb; out = ob; M = Mb; }
    const int nt = (M + GTILE - 1) / GTILE;
    if (t0 >= nt) return;

    // B-slice resident in registers: breg[ct][kt] = 8 bf16 at k=kt*32+quad*8 of col wid*32+ct*16+l16
    bf16x8 breg[2][8];
#pragma unroll
    for (int ct = 0; ct < 2; ++ct)
#pragma unroll
        for (int kt = 0; kt < 8; ++kt)
            breg[ct][kt] = *(const bf16x8*)(
                Wc + (size_t)(wid * 32 + ct * 16 + l16) * 256 + kt * 32 + quad * 8);

    const float bcol0 = bias[wid * 32 + l16];
    const float bcol1 = bias[wid * 32 + 16 + l16];
    const int sw = l16 & 7;

    // tile-invariant staging decode (per lane): which (row, swizzled-src-chunk)
    int a0row[2], a0sc[2];      // A0: 2 wave-calls, elem offsets (bf16)
#pragma unroll
    for (int c = 0; c < 2; ++c) {
        int o  = wid * 2048 + c * 1024 + lane * 16;   // [0, 8192)
        int row = o >> 8;
        int ch  = (o >> 4) & 15;
        a0row[c] = row;
        a0sc[c]  = (ch ^ (row & 7)) * 8;
    }
    int a1row[4], a1sc[4];      // A1: 4 wave-calls, elem offsets (f32)
#pragma unroll
    for (int c = 0; c < 4; ++c) {
        int o  = wid * 4096 + c * 1024 + lane * 16;   // [0, 16384)
        int row = o >> 9;
        int ch  = (o >> 4) & 31;
        a1row[c] = row;
        a1sc[c]  = (ch ^ (row & 7)) * 4;
    }

    auto STAGE = [&](int b, int t) {
        const int r0 = t * GTILE;
        char* base = smem + b * LDSBUF;
#pragma unroll
        for (int c = 0; c < 2; ++c) {
            int grow = r0 + a0row[c]; if (grow >= M) grow = M - 1;
            gl_lds16(A0 + (size_t)grow * DIM + a0sc[c],
                     base + wid * 2048 + c * 1024);
        }
#pragma unroll
        for (int c = 0; c < 4; ++c) {
            int grow = r0 + a1row[c]; if (grow >= M) grow = M - 1;
            gl_lds16(A1 + (size_t)grow * DIM + a1sc[c],
                     base + A0BYTES + wid * 4096 + c * 1024);
        }
    };

    auto COMPUTE = [&](int b, int t) {
        const int r0 = t * GTILE;
        const char* a0base = smem + b * LDSBUF;
        const char* a1base = a0base + A0BYTES;
        f32x4 acc[2][2];
#pragma unroll
        for (int rt = 0; rt < 2; ++rt) {
            acc[rt][0] = (f32x4){0.f, 0.f, 0.f, 0.f};
            acc[rt][1] = (f32x4){0.f, 0.f, 0.f, 0.f};
        }
#pragma unroll
        for (int rt = 0; rt < 2; ++rt) {
            const int row = rt * 16 + l16;
            bf16x8 alo[4];
#pragma unroll
            for (int kt = 0; kt < 4; ++kt)
                alo[kt] = *(const bf16x8*)(a0base + row * 256 + ((kt * 4 + quad) ^ sw) * 16);
#pragma unroll
            for (int kt = 0; kt < 4; ++kt) {
                acc[rt][0] = __builtin_amdgcn_mfma_f32_16x16x32_bf16(alo[kt], breg[0][kt], acc[rt][0], 0, 0, 0);
                acc[rt][1] = __builtin_amdgcn_mfma_f32_16x16x32_bf16(alo[kt], breg[1][kt], acc[rt][1], 0, 0, 0);
            }
#pragma unroll
            for (int kt = 0; kt < 4; ++kt) {
                const int cc = kt * 8 + quad * 2;
                float4 x0 = *(const float4*)(a1base + row * 512 + ((cc)     ^ sw) * 16);
                float4 x1 = *(const float4*)(a1base + row * 512 + ((cc + 1) ^ sw) * 16);
                bf16x8 ah;
                ah[0] = (bf16_t)x0.x; ah[1] = (bf16_t)x0.y;
                ah[2] = (bf16_t)x0.z; ah[3] = (bf16_t)x0.w;
                ah[4] = (bf16_t)x1.x; ah[5] = (bf16_t)x1.y;
                ah[6] = (bf16_t)x1.z; ah[7] = (bf16_t)x1.w;
                acc[rt][0] = __builtin_amdgcn_mfma_f32_16x16x32_bf16(ah, breg[0][kt + 4], acc[rt][0], 0, 0, 0);
                acc[rt][1] = __builtin_amdgcn_mfma_f32_16x16x32_bf16(ah, breg[1][kt + 4], acc[rt][1], 0, 0, 0);
            }
        }
        // epilogue: C/D layout col = lane&15, row = quad*4 + reg
#pragma unroll
        for (int ct = 0; ct < 2; ++ct) {
            const int col = wid * 32 + ct * 16 + l16;
            const float bv = ct ? bcol1 : bcol0;
#pragma unroll
            for (int rt = 0; rt < 2; ++rt)
#pragma unroll
                for (int r = 0; r < 4; ++r) {
                    int row = r0 + rt * 16 + quad * 4 + r;
                    if (row < M) {
                        float v = acc[rt][ct][r] + bv;
                        if (RELU) v = fmaxf(v, 0.f);
                        out[(size_t)row * DIM + col] = v;
                    }
                }
        }
    };

    STAGE(0, t0);
    int bufi = 0;
    for (int t = t0; t < nt; t += gs, bufi ^= 1) {
        const int nxt = t + gs;
        if (nxt < nt) {
            STAGE(bufi ^ 1, nxt);
            asm volatile("s_waitcnt vmcnt(6)" ::: "memory");   // current tile staged; next 6 stay in flight
        } else {
            asm volatile("s_waitcnt vmcnt(0)" ::: "memory");
        }
        __builtin_amdgcn_s_barrier();          // all waves' quarters visible
        COMPUTE(bufi, t);
        __builtin_amdgcn_s_barrier();          // all waves done reading before next STAGE overwrites
        __builtin_amdgcn_sched_barrier(0);
    }
}

// ---------------- launch ----------------
extern "C" void kernel_launch(void* const* d_in, const int* in_sizes, int n_in,
                              void* d_out, int out_size, void* d_ws, size_t ws_size,
                              hipStream_t stream) {
    const float* x_m = (const float*)d_in[0];
    const float* x_t = (const float*)d_in[1];
    const float* Wl  = (const float*)d_in[2];
    const float* bl  = (const float*)d_in[3];
    const float* Wr  = (const float*)d_in[4];
    const int* e_mt  = (const int*)d_in[5];
    const int* e_tm  = (const int*)d_in[6];

    const int Mm = in_sizes[0] / DIM;     // 100000
    const int Mt = in_sizes[1] / DIM;     // 100000
    const int E  = in_sizes[5] / 2;       // 400000
    const int NBt = (Mt + 255) / 256;
    const int NBm = (Mm + 255) / 256;

    float* out_m = (float*)d_out;
    float* out_t = (float*)d_out + (size_t)Mm * DIM;

    char* ws = (char*)d_ws;
    size_t off = 0;
    auto alloc = [&](size_t bytes) -> void* {
        void* p = ws + off;
        off += (bytes + 255) & ~(size_t)255;
        return p;
    };
    float*  xm2    = (float*)alloc((size_t)Mm * DIM * 4);
    float*  xt2    = (float*)alloc((size_t)Mt * DIM * 4);
    bf16_t* aggT   = (bf16_t*)alloc((size_t)Mt * DIM * 2);
    bf16_t* aggM   = (bf16_t*)alloc((size_t)Mm * DIM * 2);
    int*    cnt_t  = (int*)alloc((size_t)Mt * 4);
    int*    cnt_m  = (int*)alloc((size_t)Mm * 4);
    int*    rs_t   = (int*)alloc((size_t)Mt * 4);
    int*    rs_m   = (int*)alloc((size_t)Mm * 4);
    int*    cur_tb = (int*)alloc((size_t)Mt * 4);
    int*    cur_mb = (int*)alloc((size_t)Mm * 4);
    int*    part_t = (int*)alloc((size_t)Mt * 4);
    int*    part_m = (int*)alloc((size_t)Mm * 4);
    int*    bsum_t = (int*)alloc((size_t)NBt * 4);
    int*    bsum_m = (int*)alloc((size_t)NBm * 4);
    int*    csr_t  = (int*)alloc((size_t)E * 4);
    int*    csr_m  = (int*)alloc((size_t)E * 4);
    bf16_t* Wc     = (bf16_t*)alloc((size_t)6 * 128 * 256 * 2);

    // ---- per-launch structure prep ----
    hipMemsetAsync(cnt_t, 0, (size_t)Mt * 4, stream);
    hipMemsetAsync(cnt_m, 0, (size_t)Mm * 4, stream);

    const int PB = (6 * 128 * 256 + 255) / 256;               // prep_weights blocks
    const int CB = (2 * E + 255) / 256;                        // count blocks
    prep_count<<<PB + CB, 256, 0, stream>>>(Wl, Wr, Wc, e_mt + E, cnt_t, e_tm + E, cnt_m, E, PB);

    scan_local2<<<NBt + NBm, 256, 0, stream>>>(cnt_t, part_t, bsum_t, Mt, NBt,
                                               cnt_m, part_m, bsum_m, Mm);
    scan_blocks2<<<2, 256, 0, stream>>>(bsum_t, NBt, bsum_m, NBm);
    add_offsets2<<<NBt + NBm, 256, 0, stream>>>(part_t, bsum_t, rs_t, cur_tb, Mt, NBt,
                                                part_m, bsum_m, rs_m, cur_mb, Mm);
    bin_edges2<<<(2 * E + 255) / 256, 256, 0, stream>>>(e_mt, e_mt + E, cur_tb, csr_t,
                                                        e_tm, e_tm + E, cur_mb, csr_m, E);

    // merged gather grid: interleaved sides, 1 row per half-wave, 4 waves/block
    const int wT = (Mt + 1) / 2, wM = (Mm + 1) / 2;
    const int gwaves = 2 * ((wT > wM) ? wT : wM);
    const int gblocks = (gwaves + 3) / 4;

    // merged gemm grid: even, full residency (3 blk/CU x 256 CU)
    int GG = 768;
    {
        int ntT = (Mt + GTILE - 1) / GTILE, ntM = (Mm + GTILE - 1) / GTILE;
        int need = 2 * ((ntT > ntM) ? ntT : ntM);
        if (GG > need) GG = need;
        GG &= ~1;
        if (GG < 2) GG = 2;
    }

    const float* cm = x_m;
    const float* ct = x_t;
    for (int layer = 0; layer < 3; ++layer) {
        float *nxt_m, *nxt_t;
        if (layer == 1) { nxt_m = xm2;   nxt_t = xt2;   }
        else            { nxt_m = out_m; nxt_t = out_t; }
        const float* biasT = bl + ((size_t)layer * 2 + 0) * DIM;
        const float* biasM = bl + ((size_t)layer * 2 + 1) * DIM;
        const bf16_t* WcT = Wc + ((size_t)layer * 2 + 0) * 128 * 256;
        const bf16_t* WcM = Wc + ((size_t)layer * 2 + 1) * 128 * 256;

        // both aggregations in one dispatch (sides interleaved per wave)
        gather2<<<gblocks, 256, 0, stream>>>(cm, rs_t, cnt_t, csr_t, aggT, Mt,
                                             ct, rs_m, cnt_m, csr_m, aggM, Mm);
        // both GEMMs in one persistent dispatch (sides interleaved per block)
        if (layer < 2)
            gemm2<true ><<<GG, 256, 0, stream>>>(aggT, ct, WcT, biasT, nxt_t, Mt,
                                                 aggM, cm, WcM, biasM, nxt_m, Mm);
        else
            gemm2<false><<<GG, 256, 0, stream>>>(aggT, ct, WcT, biasT, nxt_t, Mt,
                                                 aggM, cm, WcM, biasM, nxt_m, Mm);

        cm = nxt_m;
        ct = nxt_t;
    }
}

// Round 5
// 511.408 us; speedup vs baseline: 1.6167x; 1.1090x over previous
//
#include <hip/hip_runtime.h>
#include <hip/hip_bf16.h>

typedef __bf16 bf16_t;
typedef __attribute__((ext_vector_type(4))) __bf16 bf16x4;
typedef __attribute__((ext_vector_type(8))) __bf16 bf16x8;
typedef __attribute__((ext_vector_type(4))) float f32x4;

#define DIM 128
#define GTILE 32

// async global->LDS, 16B per lane. LDS dest = wave-uniform base + lane*16.
__device__ __forceinline__ void gl_lds16(const void* g, void* l) {
    __builtin_amdgcn_global_load_lds(
        (const __attribute__((address_space(1))) unsigned int*)g,
        (__attribute__((address_space(3))) unsigned int*)l, 16, 0, 0);
}

// ------------- merged weight-prep + degree count (independent work) -------------
__global__ void prep_count(const float* __restrict__ Wl, const float* __restrict__ Wr,
                           bf16_t* __restrict__ Wc,
                           const int* __restrict__ dA, int* __restrict__ cA,
                           const int* __restrict__ dB, int* __restrict__ cB,
                           int E, int PB) {
    int blk = blockIdx.x;
    if (blk < PB) {
        int idx = blk * 256 + threadIdx.x;           // over 6*128*256
        if (idx >= 6 * 128 * 256) return;
        int k = idx & 255;
        int n = (idx >> 8) & 127;
        int s = idx >> 15;                            // 0..5
        float v;
        if (k < 128) v = Wl[((size_t)s * 128 + n) * 128 + k];
        else         v = Wr[((size_t)s * 128 + n) * 128 + (k - 128)];
        Wc[idx] = (bf16_t)v;
    } else {
        int i = (blk - PB) * 256 + threadIdx.x;
        if (i < E) atomicAdd(&cA[dA[i]], 1);
        else if (i < 2 * E) atomicAdd(&cB[dB[i - E]], 1);
    }
}

// ---------------- CSR build: both sides in each scan stage ----------------
__global__ __launch_bounds__(256) void scan_local2(
    const int* __restrict__ cntA, int* __restrict__ partA, int* __restrict__ bsumA,
    int MA, int NBA,
    const int* __restrict__ cntB, int* __restrict__ partB, int* __restrict__ bsumB,
    int MB) {
    int blk = blockIdx.x;
    const int* cnt; int* partial; int* blocksum; int M; int b;
    if (blk < NBA) { cnt = cntA; partial = partA; blocksum = bsumA; M = MA; b = blk; }
    else           { cnt = cntB; partial = partB; blocksum = bsumB; M = MB; b = blk - NBA; }
    __shared__ int sdata[256];
    int i = b * 256 + threadIdx.x;
    int v = (i < M) ? cnt[i] : 0;
    sdata[threadIdx.x] = v;
    __syncthreads();
    for (int off = 1; off < 256; off <<= 1) {
        int t = (threadIdx.x >= off) ? sdata[threadIdx.x - off] : 0;
        __syncthreads();
        sdata[threadIdx.x] += t;
        __syncthreads();
    }
    int incl = sdata[threadIdx.x];
    if (i < M) partial[i] = incl - v;
    if (threadIdx.x == 255) blocksum[b] = incl;
}

__global__ __launch_bounds__(256) void scan_blocks2(int* __restrict__ bsA, int NA,
                                                    int* __restrict__ bsB, int NBcnt) {
    int* blocksum = blockIdx.x ? bsB : bsA;
    int NB = blockIdx.x ? NBcnt : NA;
    __shared__ int sdata[256];
    __shared__ int running;
    if (threadIdx.x == 0) running = 0;
    __syncthreads();
    for (int base = 0; base < NB; base += 256) {
        int i = base + threadIdx.x;
        int v = (i < NB) ? blocksum[i] : 0;
        sdata[threadIdx.x] = v;
        __syncthreads();
        for (int off = 1; off < 256; off <<= 1) {
            int t = (threadIdx.x >= off) ? sdata[threadIdx.x - off] : 0;
            __syncthreads();
            sdata[threadIdx.x] += t;
            __syncthreads();
        }
        int incl = sdata[threadIdx.x];
        int r = running;
        __syncthreads();
        if (i < NB) blocksum[i] = incl - v + r;
        if (threadIdx.x == 0) running = r + sdata[255];
        __syncthreads();
    }
}

__global__ __launch_bounds__(256) void add_offsets2(
    const int* __restrict__ pA, const int* __restrict__ bsA,
    int* __restrict__ rsA, int* __restrict__ curA, int MA, int NBA,
    const int* __restrict__ pB, const int* __restrict__ bsB,
    int* __restrict__ rsB, int* __restrict__ curB, int MB) {
    int blk = blockIdx.x;
    const int *partial, *blocksum; int *rowstart, *cursor; int M, b;
    if (blk < NBA) { partial = pA; blocksum = bsA; rowstart = rsA; cursor = curA; M = MA; b = blk; }
    else           { partial = pB; blocksum = bsB; rowstart = rsB; cursor = curB; M = MB; b = blk - NBA; }
    int i = b * 256 + threadIdx.x;
    if (i < M) {
        int rs = partial[i] + blocksum[i >> 8];
        rowstart[i] = rs;
        cursor[i] = rs;
    }
}

__global__ void bin_edges2(const int* __restrict__ sA, const int* __restrict__ dA,
                           int* __restrict__ curA, int* __restrict__ csrA,
                           const int* __restrict__ sB, const int* __restrict__ dB,
                           int* __restrict__ curB, int* __restrict__ csrB, int E) {
    int e = blockIdx.x * blockDim.x + threadIdx.x;
    if (e < E) {
        int d = dA[e];
        int pos = atomicAdd(&curA[d], 1);
        csrA[pos] = sA[e];
    } else if (e < 2 * E) {
        int i = e - E;
        int d = dB[i];
        int pos = atomicAdd(&curB[d], 1);
        csrB[pos] = sB[i];
    }
}

// ---------------- fused gather-mean + GEMM, persistent, both sides --------------
// Per 32-row tile: gather phase computes mean of neighbor rows (f32 accumulate)
// directly into the swizzled A0 LDS buffer; A1 (x_dst) is prefetched via
// global_load_lds double-buffer (latency hidden under the gather phase); then
// MFMA: out = A0@Wl.T + bias + bf16(A1)@Wr.T (+ReLU).
// MODE 0: L0  (gather src f32, A1 f32, out bf16, relu)   -- bit-identical math
// MODE 1: mid (gather src bf16, A1 bf16, out bf16, relu) -- gather sums bf16 rows
// MODE 2: last(gather src bf16, A1 bf16, out f32, no relu)
#define A0SZ 8192               // 32 rows * 256B bf16

template <int MODE>
__global__ __launch_bounds__(256, 3) void fused2(
    const void* __restrict__ gsA, const int* __restrict__ rsA,
    const int* __restrict__ cnA, const int* __restrict__ csA,
    const void* __restrict__ a1A, const bf16_t* __restrict__ WcA,
    const float* __restrict__ bA, void* __restrict__ oA, int Ma,
    const void* __restrict__ gsB, const int* __restrict__ rsB,
    const int* __restrict__ cnB, const int* __restrict__ csB,
    const void* __restrict__ a1B, const bf16_t* __restrict__ WcB,
    const float* __restrict__ bB, void* __restrict__ oB, int Mb) {
    constexpr int A1SZ = (MODE == 0) ? 16384 : 8192;   // 32 rows * 512B f32 / 256B bf16
    __shared__ char smem[A0SZ + 2 * A1SZ];

    const int tid  = threadIdx.x;
    const int wid  = tid >> 6;
    const int lane = tid & 63;
    const int quad = lane >> 4;
    const int l16  = lane & 15;

    const int side = blockIdx.x & 1;
    const int t0   = blockIdx.x >> 1;
    const int gs   = gridDim.x >> 1;       // host guarantees even grid

    const void *gsrc, *a1p; const int *rsx, *cnx, *csx;
    const bf16_t* Wc; const float* bias; void* outp; int M;
    if (side == 0) { gsrc = gsA; rsx = rsA; cnx = cnA; csx = csA; a1p = a1A;
                     Wc = WcA; bias = bA; outp = oA; M = Ma; }
    else           { gsrc = gsB; rsx = rsB; cnx = cnB; csx = csB; a1p = a1B;
                     Wc = WcB; bias = bB; outp = oB; M = Mb; }
    const int nt = (M + GTILE - 1) / GTILE;
    if (t0 >= nt) return;

    // B-slice resident in registers: breg[ct][kt] = 8 bf16 at k=kt*32+quad*8 of col wid*32+ct*16+l16
    bf16x8 breg[2][8];
#pragma unroll
    for (int ct = 0; ct < 2; ++ct)
#pragma unroll
        for (int kt = 0; kt < 8; ++kt)
            breg[ct][kt] = *(const bf16x8*)(
                Wc + (size_t)(wid * 32 + ct * 16 + l16) * 256 + kt * 32 + quad * 8);

    const float bcol0 = bias[wid * 32 + l16];
    const float bcol1 = bias[wid * 32 + 16 + l16];
    const int sw = l16 & 7;

    // A1 staging decode (tile-invariant): linear LDS dest, pre-swizzled global src
    int s_row[4], s_off[4];
    if constexpr (MODE == 0) {
#pragma unroll
        for (int c = 0; c < 4; ++c) {                  // 4 calls/wave over 16KB
            int o = wid * 4096 + c * 1024 + lane * 16;
            int row = o >> 9;
            int ch  = (o >> 4) & 31;
            s_row[c] = row;
            s_off[c] = (ch ^ (row & 7)) * 4;           // f32 elems
        }
    } else {
#pragma unroll
        for (int c = 0; c < 2; ++c) {                  // 2 calls/wave over 8KB
            int o = wid * 2048 + c * 1024 + lane * 16;
            int row = o >> 8;
            int ch  = (o >> 4) & 15;
            s_row[c] = row;
            s_off[c] = (ch ^ (row & 7)) * 8;           // bf16 elems
        }
    }

    auto STAGE = [&](int b, int t) {
        const int r0 = t * GTILE;
        char* base = smem + A0SZ + b * A1SZ;
        if constexpr (MODE == 0) {
            const float* A1f = (const float*)a1p;
#pragma unroll
            for (int c = 0; c < 4; ++c) {
                int grow = r0 + s_row[c]; if (grow >= M) grow = M - 1;
                gl_lds16(A1f + (size_t)grow * DIM + s_off[c],
                         base + wid * 4096 + c * 1024);
            }
        } else {
            const bf16_t* A1h = (const bf16_t*)a1p;
#pragma unroll
            for (int c = 0; c < 2; ++c) {
                int grow = r0 + s_row[c]; if (grow >= M) grow = M - 1;
                gl_lds16(A1h + (size_t)grow * DIM + s_off[c],
                         base + wid * 2048 + c * 1024);
            }
        }
    };

    // gather phase: half-wave hw owns tile rows hw*4..hw*4+3; 32 lanes x 4 elems.
    // Batch-8 edge loop with parity accumulate (same summation order as r4 kernel).
    auto GATHER = [&](int t) {
        const int hw  = tid >> 5;
        const int l32 = tid & 31;
        char* a0 = smem;
#pragma unroll 1
        for (int rr = 0; rr < 4; ++rr) {
            int r = hw * 4 + rr;
            int d = t * GTILE + r;
            float4 acc0 = {0.f, 0.f, 0.f, 0.f};
            float4 acc1 = {0.f, 0.f, 0.f, 0.f};
            int n = 0;
            if (d < M) {
                int start = rsx[d];
                n = cnx[d];
                for (int k = 0; k < n; k += 8) {
                    int sv[8];
#pragma unroll
                    for (int j = 0; j < 8; ++j)
                        sv[j] = csx[start + min(k + j, n - 1)];
                    float4 vv[8];
                    if constexpr (MODE == 0) {
                        const float* xg = (const float*)gsrc;
#pragma unroll
                        for (int j = 0; j < 8; ++j)
                            vv[j] = ((const float4*)(xg + (size_t)sv[j] * DIM))[l32];
                    } else {
                        const bf16_t* xg = (const bf16_t*)gsrc;
#pragma unroll
                        for (int j = 0; j < 8; ++j) {
                            bf16x4 b4 = *(const bf16x4*)(xg + (size_t)sv[j] * DIM + l32 * 4);
                            vv[j] = (float4){(float)b4[0], (float)b4[1],
                                             (float)b4[2], (float)b4[3]};
                        }
                    }
#pragma unroll
                    for (int j = 0; j < 8; j += 2) {
                        float w0 = (k + j     < n) ? 1.f : 0.f;
                        float w1 = (k + j + 1 < n) ? 1.f : 0.f;
                        acc0.x += vv[j].x * w0; acc0.y += vv[j].y * w0;
                        acc0.z += vv[j].z * w0; acc0.w += vv[j].w * w0;
                        acc1.x += vv[j + 1].x * w1; acc1.y += vv[j + 1].y * w1;
                        acc1.z += vv[j + 1].z * w1; acc1.w += vv[j + 1].w * w1;
                    }
                }
            }
            float invn = 1.0f / (float)max(n, 1);
            bf16x4 res;
            res[0] = (bf16_t)((acc0.x + acc1.x) * invn);
            res[1] = (bf16_t)((acc0.y + acc1.y) * invn);
            res[2] = (bf16_t)((acc0.z + acc1.z) * invn);
            res[3] = (bf16_t)((acc0.w + acc1.w) * invn);
            // swizzled A0 write: row r, chunk (l32>>1)^(r&7), half (l32&1)
            *(bf16x4*)(a0 + r * 256 + (((l32 >> 1) ^ (r & 7)) << 4) + ((l32 & 1) << 3)) = res;
        }
    };

    auto COMPUTE = [&](int b, int t) {
        const int r0 = t * GTILE;
        const char* a0base = smem;
        const char* a1base = smem + A0SZ + b * A1SZ;
        f32x4 acc[2][2];
#pragma unroll
        for (int rt = 0; rt < 2; ++rt) {
            acc[rt][0] = (f32x4){0.f, 0.f, 0.f, 0.f};
            acc[rt][1] = (f32x4){0.f, 0.f, 0.f, 0.f};
        }
#pragma unroll
        for (int rt = 0; rt < 2; ++rt) {
            const int row = rt * 16 + l16;
            bf16x8 alo[4];
#pragma unroll
            for (int kt = 0; kt < 4; ++kt)
                alo[kt] = *(const bf16x8*)(a0base + row * 256 + ((kt * 4 + quad) ^ sw) * 16);
#pragma unroll
            for (int kt = 0; kt < 4; ++kt) {
                acc[rt][0] = __builtin_amdgcn_mfma_f32_16x16x32_bf16(alo[kt], breg[0][kt], acc[rt][0], 0, 0, 0);
                acc[rt][1] = __builtin_amdgcn_mfma_f32_16x16x32_bf16(alo[kt], breg[1][kt], acc[rt][1], 0, 0, 0);
            }
            if constexpr (MODE == 0) {
#pragma unroll
                for (int kt = 0; kt < 4; ++kt) {
                    const int cc = kt * 8 + quad * 2;
                    float4 x0 = *(const float4*)(a1base + row * 512 + ((cc)     ^ sw) * 16);
                    float4 x1 = *(const float4*)(a1base + row * 512 + ((cc + 1) ^ sw) * 16);
                    bf16x8 ah;
                    ah[0] = (bf16_t)x0.x; ah[1] = (bf16_t)x0.y;
                    ah[2] = (bf16_t)x0.z; ah[3] = (bf16_t)x0.w;
                    ah[4] = (bf16_t)x1.x; ah[5] = (bf16_t)x1.y;
                    ah[6] = (bf16_t)x1.z; ah[7] = (bf16_t)x1.w;
                    acc[rt][0] = __builtin_amdgcn_mfma_f32_16x16x32_bf16(ah, breg[0][kt + 4], acc[rt][0], 0, 0, 0);
                    acc[rt][1] = __builtin_amdgcn_mfma_f32_16x16x32_bf16(ah, breg[1][kt + 4], acc[rt][1], 0, 0, 0);
                }
            } else {
#pragma unroll
                for (int kt = 0; kt < 4; ++kt) {
                    bf16x8 ah = *(const bf16x8*)(a1base + row * 256 + ((kt * 4 + quad) ^ sw) * 16);
                    acc[rt][0] = __builtin_amdgcn_mfma_f32_16x16x32_bf16(ah, breg[0][kt + 4], acc[rt][0], 0, 0, 0);
                    acc[rt][1] = __builtin_amdgcn_mfma_f32_16x16x32_bf16(ah, breg[1][kt + 4], acc[rt][1], 0, 0, 0);
                }
            }
        }
        // epilogue: C/D layout col = lane&15, row = quad*4 + reg
#pragma unroll
        for (int ct = 0; ct < 2; ++ct) {
            const int col = wid * 32 + ct * 16 + l16;
            const float bv = ct ? bcol1 : bcol0;
#pragma unroll
            for (int rt = 0; rt < 2; ++rt)
#pragma unroll
                for (int r = 0; r < 4; ++r) {
                    int row = r0 + rt * 16 + quad * 4 + r;
                    if (row < M) {
                        float v = acc[rt][ct][r] + bv;
                        if (MODE < 2) v = fmaxf(v, 0.f);
                        if constexpr (MODE == 2)
                            ((float*)outp)[(size_t)row * DIM + col] = v;
                        else
                            ((bf16_t*)outp)[(size_t)row * DIM + col] = (bf16_t)v;
                    }
                }
        }
    };

    STAGE(0, t0);
    int cur = 0;
    for (int t = t0; t < nt; t += gs, cur ^= 1) {
        const int nxt = t + gs;
        if (nxt < nt) STAGE(cur ^ 1, nxt);     // prefetch next A1; completes under gather
        GATHER(t);
        __syncthreads();                        // A0 + A1[cur] visible
        COMPUTE(cur, t);
        __syncthreads();                        // reads done before next overwrite
    }
}

// ---------------- launch ----------------
extern "C" void kernel_launch(void* const* d_in, const int* in_sizes, int n_in,
                              void* d_out, int out_size, void* d_ws, size_t ws_size,
                              hipStream_t stream) {
    const float* x_m = (const float*)d_in[0];
    const float* x_t = (const float*)d_in[1];
    const float* Wl  = (const float*)d_in[2];
    const float* bl  = (const float*)d_in[3];
    const float* Wr  = (const float*)d_in[4];
    const int* e_mt  = (const int*)d_in[5];
    const int* e_tm  = (const int*)d_in[6];

    const int Mm = in_sizes[0] / DIM;     // 100000
    const int Mt = in_sizes[1] / DIM;     // 100000
    const int E  = in_sizes[5] / 2;       // 400000
    const int NBt = (Mt + 255) / 256;
    const int NBm = (Mm + 255) / 256;

    float* out_m = (float*)d_out;
    float* out_t = (float*)d_out + (size_t)Mm * DIM;

    char* ws = (char*)d_ws;
    size_t off = 0;
    auto alloc = [&](size_t bytes) -> void* {
        void* p = ws + off;
        off += (bytes + 255) & ~(size_t)255;
        return p;
    };
    bf16_t* xb_m0  = (bf16_t*)alloc((size_t)Mm * DIM * 2);
    bf16_t* xb_t0  = (bf16_t*)alloc((size_t)Mt * DIM * 2);
    bf16_t* xb_m1  = (bf16_t*)alloc((size_t)Mm * DIM * 2);
    bf16_t* xb_t1  = (bf16_t*)alloc((size_t)Mt * DIM * 2);
    int*    cnt_t  = (int*)alloc((size_t)Mt * 4);
    int*    cnt_m  = (int*)alloc((size_t)Mm * 4);
    int*    rs_t   = (int*)alloc((size_t)Mt * 4);
    int*    rs_m   = (int*)alloc((size_t)Mm * 4);
    int*    cur_tb = (int*)alloc((size_t)Mt * 4);
    int*    cur_mb = (int*)alloc((size_t)Mm * 4);
    int*    part_t = (int*)alloc((size_t)Mt * 4);
    int*    part_m = (int*)alloc((size_t)Mm * 4);
    int*    bsum_t = (int*)alloc((size_t)NBt * 4);
    int*    bsum_m = (int*)alloc((size_t)NBm * 4);
    int*    csr_t  = (int*)alloc((size_t)E * 4);
    int*    csr_m  = (int*)alloc((size_t)E * 4);
    bf16_t* Wc     = (bf16_t*)alloc((size_t)6 * 128 * 256 * 2);

    // ---- per-launch structure prep ----
    hipMemsetAsync(cnt_t, 0, (size_t)Mt * 4, stream);
    hipMemsetAsync(cnt_m, 0, (size_t)Mm * 4, stream);

    const int PB = (6 * 128 * 256 + 255) / 256;
    const int CB = (2 * E + 255) / 256;
    prep_count<<<PB + CB, 256, 0, stream>>>(Wl, Wr, Wc, e_mt + E, cnt_t, e_tm + E, cnt_m, E, PB);

    scan_local2<<<NBt + NBm, 256, 0, stream>>>(cnt_t, part_t, bsum_t, Mt, NBt,
                                               cnt_m, part_m, bsum_m, Mm);
    scan_blocks2<<<2, 256, 0, stream>>>(bsum_t, NBt, bsum_m, NBm);
    add_offsets2<<<NBt + NBm, 256, 0, stream>>>(part_t, bsum_t, rs_t, cur_tb, Mt, NBt,
                                                part_m, bsum_m, rs_m, cur_mb, Mm);
    bin_edges2<<<(2 * E + 255) / 256, 256, 0, stream>>>(e_mt, e_mt + E, cur_tb, csr_t,
                                                        e_tm, e_tm + E, cur_mb, csr_m, E);

    // fused grid: even, full residency (3 blk/CU x 256 CU), sides interleaved
    int GG = 768;
    {
        int ntT = (Mt + GTILE - 1) / GTILE, ntM = (Mm + GTILE - 1) / GTILE;
        int need = 2 * ((ntT > ntM) ? ntT : ntM);
        if (GG > need) GG = need;
        GG &= ~1;
        if (GG < 2) GG = 2;
    }

    const float* biasT0 = bl + 0 * DIM;  const float* biasM0 = bl + 1 * DIM;
    const float* biasT1 = bl + 2 * DIM;  const float* biasM1 = bl + 3 * DIM;
    const float* biasT2 = bl + 4 * DIM;  const float* biasM2 = bl + 5 * DIM;
    const bf16_t* WcT0 = Wc + 0 * 128 * 256;  const bf16_t* WcM0 = Wc + 1 * 128 * 256;
    const bf16_t* WcT1 = Wc + 2 * 128 * 256;  const bf16_t* WcM1 = Wc + 3 * 128 * 256;
    const bf16_t* WcT2 = Wc + 4 * 128 * 256;  const bf16_t* WcM2 = Wc + 5 * 128 * 256;

    // Layer 0: gather f32 originals, A1 f32 originals, out bf16 (+relu)
    fused2<0><<<GG, 256, 0, stream>>>(
        x_m, rs_t, cnt_t, csr_t, x_t, WcT0, biasT0, xb_t0, Mt,
        x_t, rs_m, cnt_m, csr_m, x_m, WcM0, biasM0, xb_m0, Mm);
    // Layer 1: all bf16, out bf16 (+relu)
    fused2<1><<<GG, 256, 0, stream>>>(
        xb_m0, rs_t, cnt_t, csr_t, xb_t0, WcT1, biasT1, xb_t1, Mt,
        xb_t0, rs_m, cnt_m, csr_m, xb_m0, WcM1, biasM1, xb_m1, Mm);
    // Layer 2: bf16 in, f32 out, no relu
    fused2<2><<<GG, 256, 0, stream>>>(
        xb_m1, rs_t, cnt_t, csr_t, xb_t1, WcT2, biasT2, out_t, Mt,
        xb_t1, rs_m, cnt_m, csr_m, xb_m1, WcM2, biasM2, out_m, Mm);
}